// Round 9
// baseline (220.193 us; speedup 1.0000x reference)
//
#include <hip/hip_runtime.h>
#include <hip/hip_bf16.h>
#include <math.h>

#define B_ 32
#define N_ 16384
#define D_ 128
#define NEG_SLOPE 0.2f
#define CHUNKS 32      // 1024 blocks = 4/CU
#define TILES 8        // 64-row tiles per chunk (512 rows/chunk)

typedef __attribute__((ext_vector_type(8))) short short8;
typedef __attribute__((ext_vector_type(4))) float f32x4;

__device__ __forceinline__ unsigned pk2(float lo, float hi) {
    union { __hip_bfloat162 b; unsigned u; } t;
    t.b = __float22bfloat162_rn(make_float2(lo, hi));
    return t.u;
}
__device__ __forceinline__ short8 pack8(float4 x, float4 y) {
    union { unsigned u[4]; short8 s; } r;
    r.u[0] = pk2(x.x, x.y); r.u[1] = pk2(x.z, x.w);
    r.u[2] = pk2(y.x, y.y); r.u[3] = pk2(y.z, y.w);
    return r.s;
}

// issue tile tt's 8 global loads for this lane into reg buffer r[8]
#define ISSUE(tt, r) do {                                                   \
    const float* _src = rowp + (size_t)(tt) * 64 * D_;                      \
    _Pragma("unroll")                                                       \
    for (int kk = 0; kk < 4; ++kk) {                                        \
        (r)[2 * kk]     = *(const float4*)(_src + kk * 32);                 \
        (r)[2 * kk + 1] = *(const float4*)(_src + kk * 32 + 4);             \
    }                                                                       \
} while (0)

// per-kk pack->MFMA (short af live range); refill raw after last pack
#define PROC(raw, tt) do {                                                  \
    f32x4 acc[8] = {};                                                      \
    _Pragma("unroll")                                                       \
    for (int kk = 0; kk < 4; ++kk) {                                        \
        short8 af = pack8((raw)[2 * kk], (raw)[2 * kk + 1]); /* vmcnt */    \
        if (kk == 3 && (tt) + 1 < TILES) ISSUE((tt) + 1, raw);              \
        _Pragma("unroll")                                                   \
        for (int cf = 0; cf < 8; ++cf) {                                    \
            short8 bq = *(const short8*)&wk[((cf * 4 + kk) * 64 + lane) * 8]; \
            acc[cf] = __builtin_amdgcn_mfma_f32_16x16x32_bf16(af, bq, acc[cf], 0, 0, 0); \
        }                                                                   \
    }                                                                       \
    float lg[4];                                                            \
    _Pragma("unroll")                                                       \
    for (int j = 0; j < 4; ++j) {                                           \
        float s = 0.f;                                                      \
        _Pragma("unroll")                                                   \
        for (int cf = 0; cf < 8; ++cf) {                                    \
            float v = hq_r[cf] + acc[cf][j];                                \
            v = (v > 0.f) ? v : (NEG_SLOPE * v);                            \
            s = fmaf(v, wa_r[cf], s);                                       \
        }                                                                   \
        s += __shfl_xor(s, 1);                                              \
        s += __shfl_xor(s, 2);                                              \
        s += __shfl_xor(s, 4);                                              \
        s += __shfl_xor(s, 8);                                              \
        lg[j] = s;                                                          \
    }                                                                       \
    {                                                                       \
        int nbase = n0 + (tt) * 64 + w * 16;                                \
        if (ln == 0)                                                        \
            *(float4*)&logits[(size_t)b * N_ + nbase + g * 4] =             \
                make_float4(lg[0], lg[1], lg[2], lg[3]);                    \
    }                                                                       \
    float mt = fmaxf(fmaxf(lg[0], lg[1]), fmaxf(lg[2], lg[3]));             \
    mt = fmaxf(mt, __shfl_xor(mt, 16));                                     \
    mt = fmaxf(mt, __shfl_xor(mt, 32));                                     \
    float m_new = fmaxf(m_w, mt);                                           \
    float corr = __expf(m_w - m_new);                                       \
    l_w *= corr;                                                            \
    _Pragma("unroll")                                                       \
    for (int cf = 0; cf < 8; ++cf) accl[cf] *= corr;                        \
    _Pragma("unroll")                                                       \
    for (int j = 0; j < 4; ++j) {                                           \
        float p = __expf(lg[j] - m_new);                                    \
        l_w += (ln == 0) ? p : 0.f;                                         \
        _Pragma("unroll")                                                   \
        for (int cf = 0; cf < 8; ++cf)                                      \
            accl[cf] = fmaf(p, acc[cf][j], accl[cf]);                       \
    }                                                                       \
    m_w = m_new;                                                            \
} while (0)

// ---- fused main: hq + h_key GEMM + logits + online softmax ----
// Key loads straight into A-fragment registers (plain global loads, single
// tile-ahead, compiler-counted vmcnt). Wk in LDS fragment-contiguous
// (conflict-free ds_read_b128). Barrier-free wave-private main loop.
// 4 waves/SIMD (16 waves/CU) for streaming depth.
__global__ __launch_bounds__(256, 4) void
main_kernel(const float* __restrict__ query, const float* __restrict__ key,
            const float* __restrict__ Wq, const float* __restrict__ Wk,
            const float* __restrict__ Wa,
            float* __restrict__ logits, float* __restrict__ part) {
    __shared__ unsigned short wk[32 * 64 * 8];  // 32 frags x 64 lanes x bf16x8 = 32 KB
    __shared__ float hq_lds[D_];
    __shared__ float comb_acc[4][D_];
    __shared__ float comb_m[4], comb_l[4];

    const int b = blockIdx.y, chunk = blockIdx.x;
    const int tid = threadIdx.x;
    const int w = tid >> 6, lane = tid & 63, ln = lane & 15, g = lane >> 4;
    const int n0 = chunk * (N_ / CHUNKS);

    // ---- fill Wk fragments into LDS ----
#pragma unroll
    for (int idx = tid; idx < 2048; idx += 256) {
        int f = idx >> 6, l = idx & 63;
        int c = (f >> 2) * 16 + (l & 15);
        int k0 = (f & 3) * 32 + (l >> 4) * 8;
        const float4* p = (const float4*)(Wk + (size_t)c * D_ + k0);
        *(short8*)&wk[idx * 8] = pack8(p[0], p[1]);
    }
    // ---- hq split across waves ----
    {
        const float4* qv = (const float4*)(query + (size_t)b * D_);
#pragma unroll
        for (int cc = 0; cc < 2; ++cc) {
            int cf = w * 2 + cc;
            const float4* wv = (const float4*)(Wq + (size_t)(cf * 16 + ln) * D_ + g * 32);
            float s = 0.f;
#pragma unroll
            for (int u = 0; u < 8; ++u) {
                float4 wq = wv[u], qq = qv[g * 8 + u];
                s = fmaf(wq.x, qq.x, s); s = fmaf(wq.y, qq.y, s);
                s = fmaf(wq.z, qq.z, s); s = fmaf(wq.w, qq.w, s);
            }
            s += __shfl_xor(s, 16);
            s += __shfl_xor(s, 32);
            if (lane < 16) hq_lds[cf * 16 + ln] = s;
        }
    }
    __syncthreads();   // the only barrier before the epilogue

    float hq_r[8], wa_r[8];
#pragma unroll
    for (int cf = 0; cf < 8; ++cf) {
        hq_r[cf] = hq_lds[cf * 16 + ln];
        wa_r[cf] = Wa[cf * 16 + ln];
    }

    float m_w = -1e30f, l_w = 0.f;
    float accl[8];
#pragma unroll
    for (int cf = 0; cf < 8; ++cf) accl[cf] = 0.f;

    const float* rowp = key + ((size_t)b * N_ + n0 + w * 16 + ln) * D_ + g * 8;

    float4 raw[8];
    ISSUE(0, raw);
    for (int t = 0; t < TILES; ++t) {
        PROC(raw, t);
    }

    // ---- block combine (4 waves, disjoint row ranges) ----
#pragma unroll
    for (int cf = 0; cf < 8; ++cf) {
        accl[cf] += __shfl_xor(accl[cf], 16);
        accl[cf] += __shfl_xor(accl[cf], 32);
    }
    l_w += __shfl_xor(l_w, 1);
    l_w += __shfl_xor(l_w, 2);
    l_w += __shfl_xor(l_w, 4);
    l_w += __shfl_xor(l_w, 8);
    l_w += __shfl_xor(l_w, 16);
    l_w += __shfl_xor(l_w, 32);
    if (lane < 16) {
#pragma unroll
        for (int cf = 0; cf < 8; ++cf)
            comb_acc[w][cf * 16 + ln] = accl[cf];
    }
    if (lane == 0) { comb_m[w] = m_w; comb_l[w] = l_w; }
    __syncthreads();
    if (tid < D_ + 2) {
        float mb = fmaxf(fmaxf(comb_m[0], comb_m[1]), fmaxf(comb_m[2], comb_m[3]));
        float* pp = part + ((size_t)b * CHUNKS + chunk) * 132;
        if (tid < D_) {
            float ab = 0.f;
#pragma unroll
            for (int ww = 0; ww < 4; ++ww)
                ab = fmaf(comb_acc[ww][tid], __expf(comb_m[ww] - mb), ab);
            pp[2 + tid] = ab;
        } else if (tid == D_) {
            pp[0] = mb;
        } else {
            float lb = 0.f;
#pragma unroll
            for (int ww = 0; ww < 4; ++ww)
                lb = fmaf(comb_l[ww], __expf(comb_m[ww] - mb), lb);
            pp[1] = lb;
        }
    }
}

// ---- fused finish + e ----
__global__ __launch_bounds__(256) void
finish_e_kernel(const float* __restrict__ part, const float* __restrict__ logits,
                float* __restrict__ out) {
    const int b = blockIdx.y, s = blockIdx.x, t = threadIdx.x;
    float mb = -1e30f;
#pragma unroll
    for (int c = 0; c < CHUNKS; ++c)
        mb = fmaxf(mb, part[((size_t)b * CHUNKS + c) * 132]);
    float lb = 0.f;
#pragma unroll
    for (int c = 0; c < CHUNKS; ++c) {
        const float* pp = part + ((size_t)b * CHUNKS + c) * 132;
        lb = fmaf(pp[1], __expf(pp[0] - mb), lb);
    }
    if (s == 0 && t < D_) {
        float ac = 0.f;
#pragma unroll
        for (int c = 0; c < CHUNKS; ++c) {
            const float* pp = part + ((size_t)b * CHUNKS + c) * 132;
            ac = fmaf(pp[2 + t], __expf(pp[0] - mb), ac);
        }
        float sc = ac / lb;
        out[b * D_ + t] = (sc > 0.f) ? sc : expm1f(sc);
    }
    float inv = 1.f / lb;
    int n4 = s * 1024 + t * 4;
    float4 lg = *(const float4*)&logits[(size_t)b * N_ + n4];
    float4 e;
    e.x = __expf(lg.x - mb) * inv;
    e.y = __expf(lg.y - mb) * inv;
    e.z = __expf(lg.z - mb) * inv;
    e.w = __expf(lg.w - mb) * inv;
    *(float4*)&out[(size_t)B_ * D_ + (size_t)b * N_ + n4] = e;
}

extern "C" void kernel_launch(void* const* d_in, const int* in_sizes, int n_in,
                              void* d_out, int out_size, void* d_ws, size_t ws_size,
                              hipStream_t stream) {
    const float* query = (const float*)d_in[0];
    const float* key   = (const float*)d_in[1];
    const float* Wq    = (const float*)d_in[2];
    const float* Wk    = (const float*)d_in[3];
    const float* Wa    = (const float*)d_in[4];
    float* out = (float*)d_out;

    float* ws     = (float*)d_ws;
    float* logits = ws;                                   // B*N
    float* part   = logits + (size_t)B_ * N_;             // 32*32*132

    main_kernel<<<dim3(CHUNKS, B_), dim3(256), 0, stream>>>(
        query, key, Wq, Wk, Wa, logits, part);
    finish_e_kernel<<<dim3(16, B_), dim3(256), 0, stream>>>(part, logits, out);
}

// Round 10
// 147.963 us; speedup vs baseline: 1.4882x; 1.4882x over previous
//
#include <hip/hip_runtime.h>
#include <hip/hip_bf16.h>
#include <math.h>

#define B_ 32
#define N_ 16384
#define D_ 128
#define NEG_SLOPE 0.2f
#define CHUNKS 16      // 512 blocks = 2/CU
#define TILES 16       // 64-row tiles per chunk (16 rows per wave per tile)

typedef __attribute__((ext_vector_type(8))) short short8;
typedef __attribute__((ext_vector_type(4))) float f32x4;

__device__ __forceinline__ unsigned pk2(float lo, float hi) {
    union { __hip_bfloat162 b; unsigned u; } t;
    t.b = __float22bfloat162_rn(make_float2(lo, hi));
    return t.u;
}
__device__ __forceinline__ short8 pack8(float4 x, float4 y) {
    union { unsigned u[4]; short8 s; } r;
    r.u[0] = pk2(x.x, x.y); r.u[1] = pk2(x.z, x.w);
    r.u[2] = pk2(y.x, y.y); r.u[3] = pk2(y.z, y.w);
    return r.s;
}

// issue tile tt's 8 global loads. k-slot permutation: lane (ln,g) holds
// k = kk*32 + g*4 + {0..3} and kk*32 + 16 + g*4 + {0..3}  (full-64B-line
// coalescing per instruction; B fragments permuted identically, so MFMA
// result is unchanged).
#define ISSUE(tt, r) do {                                                   \
    const float* _src = rowp + (size_t)(tt) * 64 * D_;                      \
    _Pragma("unroll")                                                       \
    for (int kk = 0; kk < 4; ++kk) {                                        \
        (r)[2 * kk]     = *(const float4*)(_src + kk * 32);                 \
        (r)[2 * kk + 1] = *(const float4*)(_src + kk * 32 + 16);            \
    }                                                                       \
} while (0)

// per-kk pack->MFMA (short af live range); refill raw after last pack
#define PROC(raw, tt) do {                                                  \
    f32x4 acc[8] = {};                                                      \
    _Pragma("unroll")                                                       \
    for (int kk = 0; kk < 4; ++kk) {                                        \
        short8 af = pack8((raw)[2 * kk], (raw)[2 * kk + 1]); /* vmcnt */    \
        if (kk == 3 && (tt) + 1 < TILES) ISSUE((tt) + 1, raw);              \
        _Pragma("unroll")                                                   \
        for (int cf = 0; cf < 8; ++cf) {                                    \
            short8 bq = *(const short8*)&wk[((cf * 4 + kk) * 64 + lane) * 8]; \
            acc[cf] = __builtin_amdgcn_mfma_f32_16x16x32_bf16(af, bq, acc[cf], 0, 0, 0); \
        }                                                                   \
    }                                                                       \
    float lg[4];                                                            \
    _Pragma("unroll")                                                       \
    for (int j = 0; j < 4; ++j) {                                           \
        float s = 0.f;                                                      \
        _Pragma("unroll")                                                   \
        for (int cf = 0; cf < 8; ++cf) {                                    \
            float v = hq_r[cf] + acc[cf][j];                                \
            v = (v > 0.f) ? v : (NEG_SLOPE * v);                            \
            s = fmaf(v, wa_r[cf], s);                                       \
        }                                                                   \
        s += __shfl_xor(s, 1);                                              \
        s += __shfl_xor(s, 2);                                              \
        s += __shfl_xor(s, 4);                                              \
        s += __shfl_xor(s, 8);                                              \
        lg[j] = s;                                                          \
    }                                                                       \
    {                                                                       \
        int nbase = n0 + (tt) * 64 + w * 16;                                \
        if (ln == 0)                                                        \
            *(float4*)&logits[(size_t)b * N_ + nbase + g * 4] =             \
                make_float4(lg[0], lg[1], lg[2], lg[3]);                    \
    }                                                                       \
    float mt = fmaxf(fmaxf(lg[0], lg[1]), fmaxf(lg[2], lg[3]));             \
    mt = fmaxf(mt, __shfl_xor(mt, 16));                                     \
    mt = fmaxf(mt, __shfl_xor(mt, 32));                                     \
    float m_new = fmaxf(m_w, mt);                                           \
    float corr = __expf(m_w - m_new);                                       \
    l_w *= corr;                                                            \
    _Pragma("unroll")                                                       \
    for (int cf = 0; cf < 8; ++cf) accl[cf] *= corr;                        \
    _Pragma("unroll")                                                       \
    for (int j = 0; j < 4; ++j) {                                           \
        float p = __expf(lg[j] - m_new);                                    \
        l_w += (ln == 0) ? p : 0.f;                                         \
        _Pragma("unroll")                                                   \
        for (int cf = 0; cf < 8; ++cf)                                      \
            accl[cf] = fmaf(p, acc[cf][j], accl[cf]);                       \
    }                                                                       \
    m_w = m_new;                                                            \
} while (0)

// ---- fused main: hq + h_key GEMM + logits + online softmax + ticket epilogue ----
__global__ __launch_bounds__(256, 2) void
main_kernel(const float* __restrict__ query, const float* __restrict__ key,
            const float* __restrict__ Wq, const float* __restrict__ Wk,
            const float* __restrict__ Wa,
            float* __restrict__ logits, float* __restrict__ part,
            int* __restrict__ tickets, float* __restrict__ out) {
    __shared__ unsigned short wk[32 * 64 * 8];  // 32 frags x 64 lanes x bf16x8 = 32 KB
    __shared__ float hq_lds[D_];
    __shared__ float comb_acc[4][D_];
    __shared__ float comb_m[4], comb_l[4];
    __shared__ int lastFlag;

    const int b = blockIdx.y, chunk = blockIdx.x;
    const int tid = threadIdx.x;
    const int w = tid >> 6, lane = tid & 63, ln = lane & 15, g = lane >> 4;
    const int n0 = chunk * (N_ / CHUNKS);

    // ---- fill Wk fragments into LDS (k-slot permuted to match ISSUE) ----
#pragma unroll
    for (int idx = tid; idx < 2048; idx += 256) {
        int f = idx >> 6, l = idx & 63;
        int c = (f >> 2) * 16 + (l & 15);
        int base = (f & 3) * 32 + (l >> 4) * 4;
        const float* wp = Wk + (size_t)c * D_ + base;
        float4 p0 = *(const float4*)(wp);
        float4 p1 = *(const float4*)(wp + 16);
        *(short8*)&wk[idx * 8] = pack8(p0, p1);
    }
    // ---- hq split across waves ----
    {
        const float4* qv = (const float4*)(query + (size_t)b * D_);
#pragma unroll
        for (int cc = 0; cc < 2; ++cc) {
            int cf = w * 2 + cc;
            const float4* wv = (const float4*)(Wq + (size_t)(cf * 16 + ln) * D_ + g * 32);
            float s = 0.f;
#pragma unroll
            for (int u = 0; u < 8; ++u) {
                float4 wq = wv[u], qq = qv[g * 8 + u];
                s = fmaf(wq.x, qq.x, s); s = fmaf(wq.y, qq.y, s);
                s = fmaf(wq.z, qq.z, s); s = fmaf(wq.w, qq.w, s);
            }
            s += __shfl_xor(s, 16);
            s += __shfl_xor(s, 32);
            if (lane < 16) hq_lds[cf * 16 + ln] = s;
        }
    }
    __syncthreads();   // the only barrier before the combine

    float hq_r[8], wa_r[8];
#pragma unroll
    for (int cf = 0; cf < 8; ++cf) {
        hq_r[cf] = hq_lds[cf * 16 + ln];
        wa_r[cf] = Wa[cf * 16 + ln];
    }

    float m_w = -1e30f, l_w = 0.f;
    float accl[8];
#pragma unroll
    for (int cf = 0; cf < 8; ++cf) accl[cf] = 0.f;

    const float* rowp = key + ((size_t)b * N_ + n0 + w * 16 + ln) * D_ + g * 4;

    float4 raw[8];
    ISSUE(0, raw);
    for (int t = 0; t < TILES; ++t) {
        PROC(raw, t);
    }

    // ---- block combine (4 waves, disjoint row ranges) ----
#pragma unroll
    for (int cf = 0; cf < 8; ++cf) {
        accl[cf] += __shfl_xor(accl[cf], 16);
        accl[cf] += __shfl_xor(accl[cf], 32);
    }
    l_w += __shfl_xor(l_w, 1);
    l_w += __shfl_xor(l_w, 2);
    l_w += __shfl_xor(l_w, 4);
    l_w += __shfl_xor(l_w, 8);
    l_w += __shfl_xor(l_w, 16);
    l_w += __shfl_xor(l_w, 32);
    if (lane < 16) {
#pragma unroll
        for (int cf = 0; cf < 8; ++cf)
            comb_acc[w][cf * 16 + ln] = accl[cf];
    }
    if (lane == 0) { comb_m[w] = m_w; comb_l[w] = l_w; }
    __syncthreads();
    if (tid < D_ + 2) {
        float mb = fmaxf(fmaxf(comb_m[0], comb_m[1]), fmaxf(comb_m[2], comb_m[3]));
        float* pp = part + ((size_t)b * CHUNKS + chunk) * 132;
        if (tid < D_) {
            float ab = 0.f;
#pragma unroll
            for (int ww = 0; ww < 4; ++ww)
                ab = fmaf(comb_acc[ww][tid], __expf(comb_m[ww] - mb), ab);
            pp[2 + tid] = ab;
        } else if (tid == D_) {
            pp[0] = mb;
        } else {
            float lb = 0.f;
#pragma unroll
            for (int ww = 0; ww < 4; ++ww)
                lb = fmaf(comb_l[ww], __expf(comb_m[ww] - mb), lb);
            pp[1] = lb;
        }
    }

    // ---- ticket: last block per b runs the epilogue ----
    __threadfence();
    __syncthreads();
    if (tid == 0) lastFlag = (atomicAdd(&tickets[b], 1) == CHUNKS - 1) ? 1 : 0;
    __syncthreads();
    if (!lastFlag) return;
    __threadfence();

    float mb = -1e30f;
#pragma unroll
    for (int c = 0; c < CHUNKS; ++c)
        mb = fmaxf(mb, part[((size_t)b * CHUNKS + c) * 132]);
    float lb = 0.f;
#pragma unroll
    for (int c = 0; c < CHUNKS; ++c) {
        const float* pp = part + ((size_t)b * CHUNKS + c) * 132;
        lb = fmaf(pp[1], __expf(pp[0] - mb), lb);
    }
    if (tid < D_) {
        float ac = 0.f;
#pragma unroll
        for (int c = 0; c < CHUNKS; ++c) {
            const float* pp = part + ((size_t)b * CHUNKS + c) * 132;
            ac = fmaf(pp[2 + tid], __expf(pp[0] - mb), ac);
        }
        float sc = ac / lb;
        out[b * D_ + tid] = (sc > 0.f) ? sc : expm1f(sc);
    }
    float inv = 1.f / lb;
    float* eout = out + (size_t)B_ * D_ + (size_t)b * N_;
    const float* lrow = logits + (size_t)b * N_;
#pragma unroll 4
    for (int i = tid; i < N_ / 4; i += 256) {
        float4 lg = *(const float4*)&lrow[i * 4];
        float4 e;
        e.x = __expf(lg.x - mb) * inv;
        e.y = __expf(lg.y - mb) * inv;
        e.z = __expf(lg.z - mb) * inv;
        e.w = __expf(lg.w - mb) * inv;
        *(float4*)&eout[i * 4] = e;
    }
}

extern "C" void kernel_launch(void* const* d_in, const int* in_sizes, int n_in,
                              void* d_out, int out_size, void* d_ws, size_t ws_size,
                              hipStream_t stream) {
    const float* query = (const float*)d_in[0];
    const float* key   = (const float*)d_in[1];
    const float* Wq    = (const float*)d_in[2];
    const float* Wk    = (const float*)d_in[3];
    const float* Wa    = (const float*)d_in[4];
    float* out = (float*)d_out;

    float* ws     = (float*)d_ws;
    float* logits = ws;                                   // B*N
    float* part   = logits + (size_t)B_ * N_;             // 32*16*132
    int* tickets  = (int*)(part + (size_t)B_ * CHUNKS * 132);

    hipMemsetAsync(tickets, 0, B_ * sizeof(int), stream);
    main_kernel<<<dim3(CHUNKS, B_), dim3(256), 0, stream>>>(
        query, key, Wq, Wk, Wa, logits, part, tickets, out);
}

// Round 11
// 68.592 us; speedup vs baseline: 3.2102x; 2.1572x over previous
//
#include <hip/hip_runtime.h>
#include <hip/hip_bf16.h>
#include <math.h>

#define B_ 32
#define N_ 16384
#define D_ 128
#define NEG_SLOPE 0.2f
#define CHUNKS 16      // 512 blocks = 2/CU
#define TILES 16       // 64-row tiles per chunk (16 rows per wave per tile)

typedef __attribute__((ext_vector_type(8))) short short8;
typedef __attribute__((ext_vector_type(4))) float f32x4;

__device__ __forceinline__ unsigned pk2(float lo, float hi) {
    union { __hip_bfloat162 b; unsigned u; } t;
    t.b = __float22bfloat162_rn(make_float2(lo, hi));
    return t.u;
}
__device__ __forceinline__ short8 pack8(float4 x, float4 y) {
    union { unsigned u[4]; short8 s; } r;
    r.u[0] = pk2(x.x, x.y); r.u[1] = pk2(x.z, x.w);
    r.u[2] = pk2(y.x, y.y); r.u[3] = pk2(y.z, y.w);
    return r.s;
}

// issue tile tt's 8 global loads for this lane into reg buffer r[8]
#define ISSUE(tt, r) do {                                                   \
    const float* _src = rowp + (size_t)(tt) * 64 * D_;                      \
    _Pragma("unroll")                                                       \
    for (int kk = 0; kk < 4; ++kk) {                                        \
        (r)[2 * kk]     = *(const float4*)(_src + kk * 32);                 \
        (r)[2 * kk + 1] = *(const float4*)(_src + kk * 32 + 4);             \
    }                                                                       \
} while (0)

// consume raw; per-kk: pack 2 regs -> immediately reissue those 2 slots for
// tile tt+1 (smooth issue, full-tile-period latency budget per load)
#define PROC(raw, tt) do {                                                  \
    f32x4 acc[8] = {};                                                      \
    _Pragma("unroll")                                                       \
    for (int kk = 0; kk < 4; ++kk) {                                        \
        short8 af = pack8((raw)[2 * kk], (raw)[2 * kk + 1]); /* vmcnt */    \
        if ((tt) + 1 < TILES) {                                             \
            const float* _src = rowp + (size_t)((tt) + 1) * 64 * D_;        \
            (raw)[2 * kk]     = *(const float4*)(_src + kk * 32);           \
            (raw)[2 * kk + 1] = *(const float4*)(_src + kk * 32 + 4);       \
        }                                                                   \
        _Pragma("unroll")                                                   \
        for (int cf = 0; cf < 8; ++cf) {                                    \
            short8 bq = *(const short8*)&wk[((cf * 4 + kk) * 64 + lane) * 8]; \
            acc[cf] = __builtin_amdgcn_mfma_f32_16x16x32_bf16(af, bq, acc[cf], 0, 0, 0); \
        }                                                                   \
    }                                                                       \
    float lg[4];                                                            \
    _Pragma("unroll")                                                       \
    for (int j = 0; j < 4; ++j) {                                           \
        float s = 0.f;                                                      \
        _Pragma("unroll")                                                   \
        for (int cf = 0; cf < 8; ++cf) {                                    \
            float v = hq_r[cf] + acc[cf][j];                                \
            v = (v > 0.f) ? v : (NEG_SLOPE * v);                            \
            s = fmaf(v, wa_r[cf], s);                                       \
        }                                                                   \
        s += __shfl_xor(s, 1);                                              \
        s += __shfl_xor(s, 2);                                              \
        s += __shfl_xor(s, 4);                                              \
        s += __shfl_xor(s, 8);                                              \
        lg[j] = s;                                                          \
    }                                                                       \
    {                                                                       \
        int nbase = n0 + (tt) * 64 + w * 16;                                \
        if (ln == 0)                                                        \
            *(float4*)&logits[(size_t)b * N_ + nbase + g * 4] =             \
                make_float4(lg[0], lg[1], lg[2], lg[3]);                    \
    }                                                                       \
    float mt = fmaxf(fmaxf(lg[0], lg[1]), fmaxf(lg[2], lg[3]));             \
    mt = fmaxf(mt, __shfl_xor(mt, 16));                                     \
    mt = fmaxf(mt, __shfl_xor(mt, 32));                                     \
    float m_new = fmaxf(m_w, mt);                                           \
    float corr = __expf(m_w - m_new);                                       \
    l_w *= corr;                                                            \
    _Pragma("unroll")                                                       \
    for (int cf = 0; cf < 8; ++cf) accl[cf] *= corr;                        \
    _Pragma("unroll")                                                       \
    for (int j = 0; j < 4; ++j) {                                           \
        float p = __expf(lg[j] - m_new);                                    \
        l_w += (ln == 0) ? p : 0.f;                                         \
        _Pragma("unroll")                                                   \
        for (int cf = 0; cf < 8; ++cf)                                      \
            accl[cf] = fmaf(p, acc[cf][j], accl[cf]);                       \
    }                                                                       \
    m_w = m_new;                                                            \
} while (0)

// ---- fused main: hq + h_key GEMM + logits + online softmax ----
// Key loads straight into A-fragment registers (plain global loads, single
// tile-ahead, per-kk smoothed reissue, compiler-counted vmcnt). Wk in LDS
// fragment-contiguous (conflict-free ds_read_b128). Barrier-free wave-private
// main loop. Two-launch structure (no device fences: r10 lesson).
__global__ __launch_bounds__(256, 2) void
main_kernel(const float* __restrict__ query, const float* __restrict__ key,
            const float* __restrict__ Wq, const float* __restrict__ Wk,
            const float* __restrict__ Wa,
            float* __restrict__ logits, float* __restrict__ part) {
    __shared__ unsigned short wk[32 * 64 * 8];  // 32 frags x 64 lanes x bf16x8 = 32 KB
    __shared__ float hq_lds[D_];
    __shared__ float comb_acc[4][D_];
    __shared__ float comb_m[4], comb_l[4];

    const int b = blockIdx.y, chunk = blockIdx.x;
    const int tid = threadIdx.x;
    const int w = tid >> 6, lane = tid & 63, ln = lane & 15, g = lane >> 4;
    const int n0 = chunk * (N_ / CHUNKS);

    // ---- fill Wk fragments into LDS ----
#pragma unroll
    for (int idx = tid; idx < 2048; idx += 256) {
        int f = idx >> 6, l = idx & 63;
        int c = (f >> 2) * 16 + (l & 15);
        int k0 = (f & 3) * 32 + (l >> 4) * 8;
        const float4* p = (const float4*)(Wk + (size_t)c * D_ + k0);
        *(short8*)&wk[idx * 8] = pack8(p[0], p[1]);
    }
    // ---- hq split across waves ----
    {
        const float4* qv = (const float4*)(query + (size_t)b * D_);
#pragma unroll
        for (int cc = 0; cc < 2; ++cc) {
            int cf = w * 2 + cc;
            const float4* wv = (const float4*)(Wq + (size_t)(cf * 16 + ln) * D_ + g * 32);
            float s = 0.f;
#pragma unroll
            for (int u = 0; u < 8; ++u) {
                float4 wq = wv[u], qq = qv[g * 8 + u];
                s = fmaf(wq.x, qq.x, s); s = fmaf(wq.y, qq.y, s);
                s = fmaf(wq.z, qq.z, s); s = fmaf(wq.w, qq.w, s);
            }
            s += __shfl_xor(s, 16);
            s += __shfl_xor(s, 32);
            if (lane < 16) hq_lds[cf * 16 + ln] = s;
        }
    }
    __syncthreads();   // the only barrier before the epilogue

    float hq_r[8], wa_r[8];
#pragma unroll
    for (int cf = 0; cf < 8; ++cf) {
        hq_r[cf] = hq_lds[cf * 16 + ln];
        wa_r[cf] = Wa[cf * 16 + ln];
    }

    float m_w = -1e30f, l_w = 0.f;
    float accl[8];
#pragma unroll
    for (int cf = 0; cf < 8; ++cf) accl[cf] = 0.f;

    const float* rowp = key + ((size_t)b * N_ + n0 + w * 16 + ln) * D_ + g * 8;

    float4 raw[8];
    ISSUE(0, raw);
    for (int t = 0; t < TILES; ++t) {
        PROC(raw, t);
    }

    // ---- block combine (4 waves, disjoint row ranges) ----
#pragma unroll
    for (int cf = 0; cf < 8; ++cf) {
        accl[cf] += __shfl_xor(accl[cf], 16);
        accl[cf] += __shfl_xor(accl[cf], 32);
    }
    l_w += __shfl_xor(l_w, 1);
    l_w += __shfl_xor(l_w, 2);
    l_w += __shfl_xor(l_w, 4);
    l_w += __shfl_xor(l_w, 8);
    l_w += __shfl_xor(l_w, 16);
    l_w += __shfl_xor(l_w, 32);
    if (lane < 16) {
#pragma unroll
        for (int cf = 0; cf < 8; ++cf)
            comb_acc[w][cf * 16 + ln] = accl[cf];
    }
    if (lane == 0) { comb_m[w] = m_w; comb_l[w] = l_w; }
    __syncthreads();
    if (tid < D_ + 2) {
        float mb = fmaxf(fmaxf(comb_m[0], comb_m[1]), fmaxf(comb_m[2], comb_m[3]));
        float* pp = part + ((size_t)b * CHUNKS + chunk) * 132;
        if (tid < D_) {
            float ab = 0.f;
#pragma unroll
            for (int ww = 0; ww < 4; ++ww)
                ab = fmaf(comb_acc[ww][tid], __expf(comb_m[ww] - mb), ab);
            pp[2 + tid] = ab;
        } else if (tid == D_) {
            pp[0] = mb;
        } else {
            float lb = 0.f;
#pragma unroll
            for (int ww = 0; ww < 4; ++ww)
                lb = fmaf(comb_l[ww], __expf(comb_m[ww] - mb), lb);
            pp[1] = lb;
        }
    }
}

// ---- fused finish + e ----
__global__ __launch_bounds__(256) void
finish_e_kernel(const float* __restrict__ part, const float* __restrict__ logits,
                float* __restrict__ out) {
    const int b = blockIdx.y, s = blockIdx.x, t = threadIdx.x;
    float mb = -1e30f;
#pragma unroll
    for (int c = 0; c < CHUNKS; ++c)
        mb = fmaxf(mb, part[((size_t)b * CHUNKS + c) * 132]);
    float lb = 0.f;
#pragma unroll
    for (int c = 0; c < CHUNKS; ++c) {
        const float* pp = part + ((size_t)b * CHUNKS + c) * 132;
        lb = fmaf(pp[1], __expf(pp[0] - mb), lb);
    }
    if (s == 0 && t < D_) {
        float ac = 0.f;
#pragma unroll
        for (int c = 0; c < CHUNKS; ++c) {
            const float* pp = part + ((size_t)b * CHUNKS + c) * 132;
            ac = fmaf(pp[2 + t], __expf(pp[0] - mb), ac);
        }
        float sc = ac / lb;
        out[b * D_ + t] = (sc > 0.f) ? sc : expm1f(sc);
    }
    float inv = 1.f / lb;
    int n4 = s * 1024 + t * 4;
    float4 lg = *(const float4*)&logits[(size_t)b * N_ + n4];
    float4 e;
    e.x = __expf(lg.x - mb) * inv;
    e.y = __expf(lg.y - mb) * inv;
    e.z = __expf(lg.z - mb) * inv;
    e.w = __expf(lg.w - mb) * inv;
    *(float4*)&out[(size_t)B_ * D_ + (size_t)b * N_ + n4] = e;
}

extern "C" void kernel_launch(void* const* d_in, const int* in_sizes, int n_in,
                              void* d_out, int out_size, void* d_ws, size_t ws_size,
                              hipStream_t stream) {
    const float* query = (const float*)d_in[0];
    const float* key   = (const float*)d_in[1];
    const float* Wq    = (const float*)d_in[2];
    const float* Wk    = (const float*)d_in[3];
    const float* Wa    = (const float*)d_in[4];
    float* out = (float*)d_out;

    float* ws     = (float*)d_ws;
    float* logits = ws;                                   // B*N
    float* part   = logits + (size_t)B_ * N_;             // 32*16*132

    main_kernel<<<dim3(CHUNKS, B_), dim3(256), 0, stream>>>(
        query, key, Wq, Wk, Wa, logits, part);
    finish_e_kernel<<<dim3(16, B_), dim3(256), 0, stream>>>(part, logits, out);
}